// Round 5
// baseline (7188.067 us; speedup 1.0000x reference)
//
#include <hip/hip_runtime.h>
#include <hip/hip_bf16.h>
#include <stdint.h>

// Problem constants
#define TT 256
#define BB 64
#define DIN 512
#define RR 2048
#define DOUT 128
#define NTOT (RR*RR)                // 4194304
#define NKEEP 838860                // int(4194304 * (1.0 - 0.8)) in IEEE double
#define BETA 0.9f
#define VTH 1.0f

// ---------------- workspace layout ----------------
// drive : float [16384][2048]   @ 0            (134217728 B)
// mask  : u32   [256][64][64]   @ 134217728    (4 MB)  spike bitmask per (t,b)
// flags : u64   [256][64]       @ +4MB         (128 KB) 8 producer bytes per (t,b)
// hist  : u32   [256]
// state : u32   [8]   (0: prefix, 1: remaining, 2: thresh bits)
// cnts  : u32   [2]   (0: spike count, 1: active count)
// NOTE: w_rec is masked IN PLACE (harness restores pristine inputs every launch).

__global__ void k_init(uint32_t* __restrict__ p, int n) {
    int i = blockIdx.x * blockDim.x + threadIdx.x;
    int stride = gridDim.x * blockDim.x;
    for (; i < n; i += stride) p[i] = 0u;
}

// ---------------- radix select (4 passes x 8 bits, k-th largest) ----------------
__global__ void k_hist(const float* __restrict__ w_rec, uint32_t* __restrict__ hist,
                       const uint32_t* __restrict__ state, int p) {
    __shared__ uint32_t lh[256];
    lh[threadIdx.x] = 0u;
    __syncthreads();
    uint32_t prefix = (p > 0) ? state[0] : 0u;
    int sh = 24 - 8 * p;
    int i = blockIdx.x * 256 + threadIdx.x;
    int stride = gridDim.x * 256;
    for (; i < NTOT; i += stride) {
        uint32_t u = __float_as_uint(fabsf(w_rec[i]));
        bool ok = (p == 0) || ((u >> (sh + 8)) == prefix);
        if (ok) atomicAdd(&lh[(u >> sh) & 255u], 1u);
    }
    __syncthreads();
    uint32_t v = lh[threadIdx.x];
    if (v) atomicAdd(&hist[threadIdx.x], v);
}

__global__ void k_select(uint32_t* __restrict__ hist, uint32_t* __restrict__ state, int p) {
    __shared__ uint32_t lh[256];
    int tid = threadIdx.x;
    lh[tid] = hist[tid];
    hist[tid] = 0u;            // ready for next pass
    __syncthreads();
    if (tid == 0) {
        uint32_t remaining = (p == 0) ? (uint32_t)NKEEP : state[1];
        int bin = 255;
        for (; bin > 0; --bin) {
            uint32_t c = lh[bin];
            if (c >= remaining) break;
            remaining -= c;
        }
        uint32_t pref = (p == 0) ? 0u : state[0];
        pref = (pref << 8) | (uint32_t)bin;
        state[0] = pref;
        state[1] = remaining;
        if (p == 3) state[2] = pref;   // full 32-bit pattern of threshold value
    }
}

// ---------------- fused: count actives + mask w_rec in place ----------------
__global__ void k_maskcount(float* __restrict__ w, const uint32_t* __restrict__ state,
                            uint32_t* __restrict__ cnts) {
    uint32_t th = state[2];
    uint32_t c = 0;
    int i = blockIdx.x * blockDim.x + threadIdx.x;       // float4 index
    int stride = gridDim.x * blockDim.x;
    for (; i < NTOT / 4; i += stride) {
        float4 v = *(float4*)&w[i * 4];
        if ((__float_as_uint(v.x) & 0x7fffffffu) >= th) c++; else v.x = 0.0f;
        if ((__float_as_uint(v.y) & 0x7fffffffu) >= th) c++; else v.y = 0.0f;
        if ((__float_as_uint(v.z) & 0x7fffffffu) >= th) c++; else v.z = 0.0f;
        if ((__float_as_uint(v.w) & 0x7fffffffu) >= th) c++; else v.w = 0.0f;
        *(float4*)&w[i * 4] = v;
    }
    for (int off = 32; off > 0; off >>= 1) c += __shfl_down(c, off);
    if ((threadIdx.x & 63) == 0 && c) atomicAdd(&cnts[1], c);
}

// ---------------- drive GEMM: [16384,512] x [512,2048] + b_in ----------------
__global__ __launch_bounds__(256) void k_drive(const float* __restrict__ x,
                                               const float* __restrict__ w_in,
                                               const float* __restrict__ b_in,
                                               float* __restrict__ drive) {
    __shared__ float As[8][128];
    __shared__ float Bs[8][128];
    const int m0 = blockIdx.x * 128;
    const int n0 = blockIdx.y * 128;
    const int tid = threadIdx.x;
    const int tx = tid & 15, ty = tid >> 4;
    const int ar = tid >> 1;
    const int ak = (tid & 1) * 4;
    const int bk = tid >> 5;
    const int bc = (tid & 31) * 4;
    float acc[8][8];
    #pragma unroll
    for (int i = 0; i < 8; ++i)
        #pragma unroll
        for (int j = 0; j < 8; ++j) acc[i][j] = 0.0f;

    for (int k0 = 0; k0 < DIN; k0 += 8) {
        float4 av = *(const float4*)&x[(m0 + ar) * DIN + k0 + ak];
        float4 bv = *(const float4*)&w_in[(size_t)(k0 + bk) * RR + n0 + bc];
        __syncthreads();
        As[ak + 0][ar] = av.x; As[ak + 1][ar] = av.y;
        As[ak + 2][ar] = av.z; As[ak + 3][ar] = av.w;
        *(float4*)&Bs[bk][bc] = bv;
        __syncthreads();
        #pragma unroll
        for (int kk = 0; kk < 8; ++kk) {
            float a[8], b[8];
            *(float4*)&a[0] = *(const float4*)&As[kk][ty * 8];
            *(float4*)&a[4] = *(const float4*)&As[kk][ty * 8 + 4];
            *(float4*)&b[0] = *(const float4*)&Bs[kk][tx * 8];
            *(float4*)&b[4] = *(const float4*)&Bs[kk][tx * 8 + 4];
            #pragma unroll
            for (int i = 0; i < 8; ++i)
                #pragma unroll
                for (int j = 0; j < 8; ++j)
                    acc[i][j] = fmaf(a[i], b[j], acc[i][j]);
        }
    }
    float bb[8];
    #pragma unroll
    for (int j = 0; j < 8; ++j) bb[j] = b_in[n0 + tx * 8 + j];
    #pragma unroll
    for (int i = 0; i < 8; ++i) {
        size_t row = (size_t)(m0 + ty * 8 + i) * RR + n0 + tx * 8;
        float4 v0, v1;
        v0.x = acc[i][0] + bb[0]; v0.y = acc[i][1] + bb[1];
        v0.z = acc[i][2] + bb[2]; v0.w = acc[i][3] + bb[3];
        v1.x = acc[i][4] + bb[4]; v1.y = acc[i][5] + bb[5];
        v1.z = acc[i][6] + bb[6]; v1.w = acc[i][7] + bb[7];
        *(float4*)&drive[row] = v0;
        *(float4*)&drive[row + 4] = v1;
    }
}

// spread 8 bits so bit i lands at bit 4i
__device__ __forceinline__ uint32_t spread4(uint32_t x) {
    x &= 0xFFu;
    x = (x | (x << 12)) & 0x000F000Fu;
    x = (x | (x << 6))  & 0x03030303u;
    x = (x | (x << 3))  & 0x11111111u;
    return x;
}

// ---------------- recurrent scan: 512 single-wave blocks = 64 batches x 8 slices ----------
// Block = 1 wave (64 lanes x 4 contiguous cols, float4 gather). 2 blocks/CU -> two
// independent batch chains per CU; sync of one hides behind gather of the other.
// Sync: 8 producer flag BYTES per (t,b), release-stored; consumer polls one u64.
// NUMERICS: per-col chain is drive-first + ascending-row adds + V=fma(BETA,V,acc),
// identical to the passing round-3/4 kernels.
__global__ __launch_bounds__(64) void k_scan(const float* __restrict__ w_rec,
                                             const float* __restrict__ drive,
                                             uint32_t* mask, unsigned long long* flags,
                                             uint32_t* cnts) {
    __shared__ int s_list[RR];        // pre-shifted byte offsets (row*8192), 8 KB

    const int lane = threadIdx.x;     // 0..63
    const int blk = blockIdx.x;       // 0..511
    const int s = blk & 7;            // slice -> XCD (heuristic %8 round-robin)
    const int b = blk >> 3;           // batch 0..63
    const int c0 = (s << 8) + (lane << 2);          // first of this lane's 4 cols
    const char* Wp = (const char*)(w_rec + c0);

    float V0 = 0.f, V1 = 0.f, V2 = 0.f, V3 = 0.f;
    uint32_t scnt = 0;
    float4 dv = *(const float4*)&drive[(size_t)b * RR + c0];   // t = 0

    for (int t = 0; t < TT; ++t) {
        float a0 = dv.x, a1 = dv.y, a2 = dv.z, a3 = dv.w;
        if (t > 0) {
            const unsigned long long* fl = &flags[(size_t)(t - 1) * BB + b];
            while (__hip_atomic_load(fl, __ATOMIC_ACQUIRE, __HIP_MEMORY_SCOPE_AGENT)
                   != ~0ull)
                __builtin_amdgcn_s_sleep(1);
            // load batch mask (64 words, 1/lane), build ascending spike list
            uint32_t m = __hip_atomic_load(&mask[((size_t)(t - 1) * BB + b) * 64 + lane],
                                           __ATOMIC_RELAXED, __HIP_MEMORY_SCOPE_AGENT);
            int p = __popc(m);
            int off = p;
            #pragma unroll
            for (int d = 1; d < 64; d <<= 1) {
                int o = __shfl_up(off, d);
                if (lane >= d) off += o;
            }
            const int n = __shfl(off, 63);
            int e = off - p;
            int base = lane << 5;
            while (m) {
                int bit = __builtin_ctz(m);
                m &= m - 1;
                s_list[e++] = (base + bit) << 13;   // byte offset = row * 8192
            }
            __syncthreads();   // single wave: cheap; orders ds_write -> ds_read
            int i = 0;
            for (; i + 16 <= n; i += 16) {
                float4 v[16];
                #pragma unroll
                for (int j = 0; j < 16; ++j)
                    v[j] = *(const float4*)(Wp + s_list[i + j]);
                #pragma unroll
                for (int j = 0; j < 16; ++j) {
                    a0 += v[j].x; a1 += v[j].y; a2 += v[j].z; a3 += v[j].w;
                }
            }
            for (; i + 4 <= n; i += 4) {
                float4 v0 = *(const float4*)(Wp + s_list[i + 0]);
                float4 v1 = *(const float4*)(Wp + s_list[i + 1]);
                float4 v2 = *(const float4*)(Wp + s_list[i + 2]);
                float4 v3 = *(const float4*)(Wp + s_list[i + 3]);
                a0 += v0.x; a1 += v0.y; a2 += v0.z; a3 += v0.w;
                a0 += v1.x; a1 += v1.y; a2 += v1.z; a3 += v1.w;
                a0 += v2.x; a1 += v2.y; a2 += v2.z; a3 += v2.w;
                a0 += v3.x; a1 += v3.y; a2 += v3.z; a3 += v3.w;
            }
            for (; i < n; ++i) {
                float4 v = *(const float4*)(Wp + s_list[i]);
                a0 += v.x; a1 += v.y; a2 += v.z; a3 += v.w;
            }
        }

        V0 = BETA * V0 + a0;    // fma(BETA, V, drive + ascending sum)
        V1 = BETA * V1 + a1;
        V2 = BETA * V2 + a2;
        V3 = BETA * V3 + a3;
        bool sp0 = V0 > VTH, sp1 = V1 > VTH, sp2 = V2 > VTH, sp3 = V3 > VTH;
        if (sp0) V0 -= VTH;
        if (sp1) V1 -= VTH;
        if (sp2) V2 -= VTH;
        if (sp3) V3 -= VTH;

        if (t + 1 < TT)   // prefetch next drive (independent of spikes)
            dv = *(const float4*)&drive[((size_t)(t + 1) * BB + b) * RR + c0];

        unsigned long long bal0 = __ballot(sp0);
        unsigned long long bal1 = __ballot(sp1);
        unsigned long long bal2 = __ballot(sp2);
        unsigned long long bal3 = __ballot(sp3);
        if (lane < 8) {   // lane w builds mask word 8s+w (neurons 256s+32w..+31)
            uint32_t word = spread4((uint32_t)(bal0 >> (8 * lane)))
                          | (spread4((uint32_t)(bal1 >> (8 * lane))) << 1)
                          | (spread4((uint32_t)(bal2 >> (8 * lane))) << 2)
                          | (spread4((uint32_t)(bal3 >> (8 * lane))) << 3);
            __hip_atomic_store(&mask[((size_t)t * BB + b) * 64 + (s << 3) + lane],
                               word, __ATOMIC_RELAXED, __HIP_MEMORY_SCOPE_AGENT);
        }
        if (lane == 0) {
            scnt += (uint32_t)__popcll(bal0) + (uint32_t)__popcll(bal1)
                  + (uint32_t)__popcll(bal2) + (uint32_t)__popcll(bal3);
            // release: drains the wave's mask stores, then publishes flag byte s
            __hip_atomic_store((uint8_t*)&flags[(size_t)t * BB + b] + s, (uint8_t)0xFF,
                               __ATOMIC_RELEASE, __HIP_MEMORY_SCOPE_AGENT);
        }
    }

    if (lane == 0 && scnt) atomicAdd(&cnts[0], scnt);
}

// ---------------- head: logits[t,b,:] = s @ w_head + b_head (sparse gather) ----------------
__global__ __launch_bounds__(128) void k_head(const uint32_t* __restrict__ mask,
                                              const float* __restrict__ w_head,
                                              const float* __restrict__ b_head,
                                              float* __restrict__ logits) {
    __shared__ uint32_t sm[64];
    int tb = blockIdx.x;        // t*64 + b
    int tid = threadIdx.x;      // 0..127
    if (tid < 64) sm[tid] = mask[tb * 64 + tid];
    __syncthreads();
    float acc = b_head[tid];
    for (int w = 0; w < 64; ++w) {
        uint32_t m = sm[w];     // uniform per block -> no divergence
        int base = w << 5;
        while (m) {
            int bit = __builtin_ctz(m);
            m &= m - 1;
            acc += w_head[(size_t)(base + bit) * DOUT + tid];
        }
    }
    logits[(size_t)tb * DOUT + tid] = acc;
}

__global__ __launch_bounds__(128) void k_readout(const float* __restrict__ logits,
                                                 float* __restrict__ readout) {
    int b = blockIdx.x, cidx = threadIdx.x;
    float s = 0.0f;
    for (int t = 0; t < TT; ++t)
        s += logits[(size_t)t * (BB * DOUT) + b * DOUT + cidx];
    readout[b * DOUT + cidx] = s * (1.0f / (float)TT);
}

__global__ void k_scalars(const uint32_t* __restrict__ cnts, float* __restrict__ out) {
    if (threadIdx.x == 0 && blockIdx.x == 0) {
        out[BB * DOUT + TT * BB * DOUT]     = (float)cnts[0] / (float)(TT * BB * RR);
        out[BB * DOUT + TT * BB * DOUT + 1] = (float)cnts[1] / (float)NTOT;
    }
}

extern "C" void kernel_launch(void* const* d_in, const int* in_sizes, int n_in,
                              void* d_out, int out_size, void* d_ws, size_t ws_size,
                              hipStream_t stream) {
    const float* x      = (const float*)d_in[0];
    const float* w_in   = (const float*)d_in[1];
    const float* b_in   = (const float*)d_in[2];
    float*       w_rec  = (float*)d_in[3];        // masked in place (restored each launch)
    const float* w_head = (const float*)d_in[4];
    const float* b_head = (const float*)d_in[5];
    float* out = (float*)d_out;

    float*    drive = (float*)d_ws;
    uint32_t* mask  = (uint32_t*)((char*)d_ws + 134217728u);
    unsigned long long* flags = (unsigned long long*)(mask + (TT * BB * 64));
    uint32_t* hist  = (uint32_t*)(flags + TT * BB);
    uint32_t* state = hist + 256;
    uint32_t* cnts  = state + 8;

    // zero flags + hist + state + cnts (contiguous; mask fully overwritten before read)
    k_init<<<64, 256, 0, stream>>>((uint32_t*)flags, TT * BB * 2 + 256 + 8 + 2);

    for (int p = 0; p < 4; ++p) {
        k_hist<<<1024, 256, 0, stream>>>(w_rec, hist, state, p);
        k_select<<<1, 256, 0, stream>>>(hist, state, p);
    }
    k_maskcount<<<1024, 256, 0, stream>>>(w_rec, state, cnts);

    k_drive<<<dim3(128, 16), 256, 0, stream>>>(x, w_in, b_in, drive);

    k_scan<<<512, 64, 0, stream>>>(w_rec, drive, mask, flags, cnts);

    k_head<<<TT * BB, 128, 0, stream>>>(mask, w_head, b_head, out + BB * DOUT);
    k_readout<<<BB, 128, 0, stream>>>(out + BB * DOUT, out);
    k_scalars<<<1, 64, 0, stream>>>(cnts, out);
}

// Round 6
// 5007.062 us; speedup vs baseline: 1.4356x; 1.4356x over previous
//
#include <hip/hip_runtime.h>
#include <hip/hip_bf16.h>
#include <stdint.h>

// Problem constants
#define TT 256
#define BB 64
#define DIN 512
#define RR 2048
#define DOUT 128
#define NTOT (RR*RR)                // 4194304
#define NKEEP 838860                // int(4194304 * (1.0 - 0.8)) in IEEE double
#define BETA 0.9f
#define VTH 1.0f

// ---------------- workspace layout ----------------
// drive : float [16384][2048]   @ 0            (134217728 B)
// mask  : u32   [256][64][64]   @ 134217728    (4 MB)  spike bitmask per (t,b)
// flags : u64   [256][64]       @ +4MB         (128 KB) 8 producer bytes per (t,b)
// hist  : u32   [256]
// state : u32   [8]   (0: prefix, 1: remaining, 2: thresh bits)
// cnts  : u32   [2]   (0: spike count, 1: active count)
// NOTE: w_rec is masked IN PLACE (harness restores pristine inputs every launch).

__global__ void k_init(uint32_t* __restrict__ p, int n) {
    int i = blockIdx.x * blockDim.x + threadIdx.x;
    int stride = gridDim.x * blockDim.x;
    for (; i < n; i += stride) p[i] = 0u;
}

// ---------------- radix select (4 passes x 8 bits, k-th largest) ----------------
__global__ void k_hist(const float* __restrict__ w_rec, uint32_t* __restrict__ hist,
                       const uint32_t* __restrict__ state, int p) {
    __shared__ uint32_t lh[256];
    lh[threadIdx.x] = 0u;
    __syncthreads();
    uint32_t prefix = (p > 0) ? state[0] : 0u;
    int sh = 24 - 8 * p;
    int i = blockIdx.x * 256 + threadIdx.x;
    int stride = gridDim.x * 256;
    for (; i < NTOT; i += stride) {
        uint32_t u = __float_as_uint(fabsf(w_rec[i]));
        bool ok = (p == 0) || ((u >> (sh + 8)) == prefix);
        if (ok) atomicAdd(&lh[(u >> sh) & 255u], 1u);
    }
    __syncthreads();
    uint32_t v = lh[threadIdx.x];
    if (v) atomicAdd(&hist[threadIdx.x], v);
}

__global__ void k_select(uint32_t* __restrict__ hist, uint32_t* __restrict__ state, int p) {
    __shared__ uint32_t lh[256];
    int tid = threadIdx.x;
    lh[tid] = hist[tid];
    hist[tid] = 0u;            // ready for next pass
    __syncthreads();
    if (tid == 0) {
        uint32_t remaining = (p == 0) ? (uint32_t)NKEEP : state[1];
        int bin = 255;
        for (; bin > 0; --bin) {
            uint32_t c = lh[bin];
            if (c >= remaining) break;
            remaining -= c;
        }
        uint32_t pref = (p == 0) ? 0u : state[0];
        pref = (pref << 8) | (uint32_t)bin;
        state[0] = pref;
        state[1] = remaining;
        if (p == 3) state[2] = pref;   // full 32-bit pattern of threshold value
    }
}

// ---------------- fused: count actives + mask w_rec in place ----------------
__global__ void k_maskcount(float* __restrict__ w, const uint32_t* __restrict__ state,
                            uint32_t* __restrict__ cnts) {
    uint32_t th = state[2];
    uint32_t c = 0;
    int i = blockIdx.x * blockDim.x + threadIdx.x;       // float4 index
    int stride = gridDim.x * blockDim.x;
    for (; i < NTOT / 4; i += stride) {
        float4 v = *(float4*)&w[i * 4];
        if ((__float_as_uint(v.x) & 0x7fffffffu) >= th) c++; else v.x = 0.0f;
        if ((__float_as_uint(v.y) & 0x7fffffffu) >= th) c++; else v.y = 0.0f;
        if ((__float_as_uint(v.z) & 0x7fffffffu) >= th) c++; else v.z = 0.0f;
        if ((__float_as_uint(v.w) & 0x7fffffffu) >= th) c++; else v.w = 0.0f;
        *(float4*)&w[i * 4] = v;
    }
    for (int off = 32; off > 0; off >>= 1) c += __shfl_down(c, off);
    if ((threadIdx.x & 63) == 0 && c) atomicAdd(&cnts[1], c);
}

// ---------------- drive GEMM: [16384,512] x [512,2048] + b_in ----------------
__global__ __launch_bounds__(256) void k_drive(const float* __restrict__ x,
                                               const float* __restrict__ w_in,
                                               const float* __restrict__ b_in,
                                               float* __restrict__ drive) {
    __shared__ float As[8][128];
    __shared__ float Bs[8][128];
    const int m0 = blockIdx.x * 128;
    const int n0 = blockIdx.y * 128;
    const int tid = threadIdx.x;
    const int tx = tid & 15, ty = tid >> 4;
    const int ar = tid >> 1;
    const int ak = (tid & 1) * 4;
    const int bk = tid >> 5;
    const int bc = (tid & 31) * 4;
    float acc[8][8];
    #pragma unroll
    for (int i = 0; i < 8; ++i)
        #pragma unroll
        for (int j = 0; j < 8; ++j) acc[i][j] = 0.0f;

    for (int k0 = 0; k0 < DIN; k0 += 8) {
        float4 av = *(const float4*)&x[(m0 + ar) * DIN + k0 + ak];
        float4 bv = *(const float4*)&w_in[(size_t)(k0 + bk) * RR + n0 + bc];
        __syncthreads();
        As[ak + 0][ar] = av.x; As[ak + 1][ar] = av.y;
        As[ak + 2][ar] = av.z; As[ak + 3][ar] = av.w;
        *(float4*)&Bs[bk][bc] = bv;
        __syncthreads();
        #pragma unroll
        for (int kk = 0; kk < 8; ++kk) {
            float a[8], b[8];
            *(float4*)&a[0] = *(const float4*)&As[kk][ty * 8];
            *(float4*)&a[4] = *(const float4*)&As[kk][ty * 8 + 4];
            *(float4*)&b[0] = *(const float4*)&Bs[kk][tx * 8];
            *(float4*)&b[4] = *(const float4*)&Bs[kk][tx * 8 + 4];
            #pragma unroll
            for (int i = 0; i < 8; ++i)
                #pragma unroll
                for (int j = 0; j < 8; ++j)
                    acc[i][j] = fmaf(a[i], b[j], acc[i][j]);
        }
    }
    float bb[8];
    #pragma unroll
    for (int j = 0; j < 8; ++j) bb[j] = b_in[n0 + tx * 8 + j];
    #pragma unroll
    for (int i = 0; i < 8; ++i) {
        size_t row = (size_t)(m0 + ty * 8 + i) * RR + n0 + tx * 8;
        float4 v0, v1;
        v0.x = acc[i][0] + bb[0]; v0.y = acc[i][1] + bb[1];
        v0.z = acc[i][2] + bb[2]; v0.w = acc[i][3] + bb[3];
        v1.x = acc[i][4] + bb[4]; v1.y = acc[i][5] + bb[5];
        v1.z = acc[i][6] + bb[6]; v1.w = acc[i][7] + bb[7];
        *(float4*)&drive[row] = v0;
        *(float4*)&drive[row + 4] = v1;
    }
}

// ---------------- recurrent scan: 512 blocks = 64 batches x 8 col-groups ----------------
// Block = (batch b, 256-col group cg); cg = blk&7 keeps a col-group on one XCD so its
// 2 MB w_rec slice stays L2-resident. lane = column (1 V per lane), 4 waves walk the
// shared spike list with 16-deep coalesced 256 B gathers.
// SYNC: relaxed-atomic polls ONLY (acquire would buffer_inv the L2 every iteration);
// mask words are relaxed atomics (cache-bypass => coherent); flag store is release.
// NUMERICS: per-(b,c) chain = drive-first + ascending-row adds + V=fma(BETA,V,acc) --
// bit-identical to rounds 1/3/4.
__global__ __launch_bounds__(256) void k_scan(const float* __restrict__ w_rec,
                                              const float* __restrict__ drive,
                                              uint32_t* mask, unsigned long long* flags,
                                              uint32_t* cnts) {
    __shared__ __align__(16) int s_list[RR];   // byte offsets (row*8192), 8 KB
    __shared__ int s_n;
    __shared__ uint32_t s_red[4];

    const int tid = threadIdx.x;
    const int blk = blockIdx.x;       // 0..511
    const int cg = blk & 7;           // col-group -> XCD (blockIdx %8 round-robin)
    const int b = blk >> 3;           // batch 0..63
    const int col = (cg << 8) + tid;  // this thread's column
    const int w = tid >> 6;           // wave id 0..3
    const int lane = tid & 63;
    const char* Wp = (const char*)(w_rec + col);

    float V = 0.f;
    uint32_t scnt = 0;
    float dv = drive[(size_t)b * RR + col];   // t = 0

    for (int t = 0; t < TT; ++t) {
        float a = dv;                 // start from drive (bit-exact chain order)
        if (t > 0) {
            if (tid == 0) {
                const unsigned long long* fl = &flags[(size_t)(t - 1) * BB + b];
                while (__hip_atomic_load(fl, __ATOMIC_RELAXED, __HIP_MEMORY_SCOPE_AGENT)
                       != ~0ull)
                    __builtin_amdgcn_s_sleep(1);
            }
            __syncthreads();
            if (tid < 64) {   // wave 0: load batch mask, build ascending spike list
                uint32_t m = __hip_atomic_load(&mask[((size_t)(t - 1) * BB + b) * 64 + tid],
                                               __ATOMIC_RELAXED, __HIP_MEMORY_SCOPE_AGENT);
                int p = __popc(m);
                int off = p;
                #pragma unroll
                for (int d = 1; d < 64; d <<= 1) {
                    int o = __shfl_up(off, d);
                    if (tid >= d) off += o;
                }
                if (tid == 63) s_n = off;
                int e = off - p;
                int base = tid << 5;
                while (m) {
                    int bit = __builtin_ctz(m);
                    m &= m - 1;
                    s_list[e++] = (base + bit) << 13;   // byte offset = row * 8192
                }
            }
            __syncthreads();
            const int n = s_n;
            int i = 0;
            for (; i + 16 <= n; i += 16) {
                int4 o0 = *(const int4*)&s_list[i];        // LDS broadcast b128
                int4 o1 = *(const int4*)&s_list[i + 4];
                int4 o2 = *(const int4*)&s_list[i + 8];
                int4 o3 = *(const int4*)&s_list[i + 12];
                float v[16];
                v[0]  = *(const float*)(Wp + o0.x);
                v[1]  = *(const float*)(Wp + o0.y);
                v[2]  = *(const float*)(Wp + o0.z);
                v[3]  = *(const float*)(Wp + o0.w);
                v[4]  = *(const float*)(Wp + o1.x);
                v[5]  = *(const float*)(Wp + o1.y);
                v[6]  = *(const float*)(Wp + o1.z);
                v[7]  = *(const float*)(Wp + o1.w);
                v[8]  = *(const float*)(Wp + o2.x);
                v[9]  = *(const float*)(Wp + o2.y);
                v[10] = *(const float*)(Wp + o2.z);
                v[11] = *(const float*)(Wp + o2.w);
                v[12] = *(const float*)(Wp + o3.x);
                v[13] = *(const float*)(Wp + o3.y);
                v[14] = *(const float*)(Wp + o3.z);
                v[15] = *(const float*)(Wp + o3.w);
                #pragma unroll
                for (int j = 0; j < 16; ++j) a += v[j];    // ascending order
            }
            for (; i + 4 <= n; i += 4) {
                int4 o = *(const int4*)&s_list[i];
                float v0 = *(const float*)(Wp + o.x);
                float v1 = *(const float*)(Wp + o.y);
                float v2 = *(const float*)(Wp + o.z);
                float v3 = *(const float*)(Wp + o.w);
                a += v0; a += v1; a += v2; a += v3;
            }
            for (; i < n; ++i) a += *(const float*)(Wp + s_list[i]);
        }

        V = BETA * V + a;             // fma(BETA, V, drive + ascending sum)
        bool sp = V > VTH;
        if (sp) V -= VTH;

        if (t + 1 < TT)   // prefetch next drive (independent of spikes)
            dv = drive[((size_t)(t + 1) * BB + b) * RR + col];

        unsigned long long bal = __ballot(sp);   // 64 cols of this wave
        if (lane == 0) {
            // u64 mask word (cg*4 + w) covers neurons [cg*256 + w*64, +64)
            __hip_atomic_store(
                (unsigned long long*)&mask[((size_t)t * BB + b) * 64] + (cg * 4 + w),
                bal, __ATOMIC_RELAXED, __HIP_MEMORY_SCOPE_AGENT);
            scnt += (uint32_t)__popcll(bal);
        }
        __syncthreads();   // drains all 4 waves' mask stores (vmcnt(0) before barrier)
        if (tid == 0)      // release: publish flag byte cg for (t,b)
            __hip_atomic_store((uint8_t*)&flags[(size_t)t * BB + b] + cg, (uint8_t)0xFF,
                               __ATOMIC_RELEASE, __HIP_MEMORY_SCOPE_AGENT);
    }

    if (lane == 0) s_red[w] = scnt;
    __syncthreads();
    if (tid == 0) {
        uint32_t s = s_red[0] + s_red[1] + s_red[2] + s_red[3];
        if (s) atomicAdd(&cnts[0], s);
    }
}

// ---------------- head: logits[t,b,:] = s @ w_head + b_head (sparse gather) ----------------
__global__ __launch_bounds__(128) void k_head(const uint32_t* __restrict__ mask,
                                              const float* __restrict__ w_head,
                                              const float* __restrict__ b_head,
                                              float* __restrict__ logits) {
    __shared__ uint32_t sm[64];
    int tb = blockIdx.x;        // t*64 + b
    int tid = threadIdx.x;      // 0..127
    if (tid < 64) sm[tid] = mask[tb * 64 + tid];
    __syncthreads();
    float acc = b_head[tid];
    for (int w = 0; w < 64; ++w) {
        uint32_t m = sm[w];     // uniform per block -> no divergence
        int base = w << 5;
        while (m) {
            int bit = __builtin_ctz(m);
            m &= m - 1;
            acc += w_head[(size_t)(base + bit) * DOUT + tid];
        }
    }
    logits[(size_t)tb * DOUT + tid] = acc;
}

__global__ __launch_bounds__(128) void k_readout(const float* __restrict__ logits,
                                                 float* __restrict__ readout) {
    int b = blockIdx.x, cidx = threadIdx.x;
    float s = 0.0f;
    for (int t = 0; t < TT; ++t)
        s += logits[(size_t)t * (BB * DOUT) + b * DOUT + cidx];
    readout[b * DOUT + cidx] = s * (1.0f / (float)TT);
}

__global__ void k_scalars(const uint32_t* __restrict__ cnts, float* __restrict__ out) {
    if (threadIdx.x == 0 && blockIdx.x == 0) {
        out[BB * DOUT + TT * BB * DOUT]     = (float)cnts[0] / (float)(TT * BB * RR);
        out[BB * DOUT + TT * BB * DOUT + 1] = (float)cnts[1] / (float)NTOT;
    }
}

extern "C" void kernel_launch(void* const* d_in, const int* in_sizes, int n_in,
                              void* d_out, int out_size, void* d_ws, size_t ws_size,
                              hipStream_t stream) {
    const float* x      = (const float*)d_in[0];
    const float* w_in   = (const float*)d_in[1];
    const float* b_in   = (const float*)d_in[2];
    float*       w_rec  = (float*)d_in[3];        // masked in place (restored each launch)
    const float* w_head = (const float*)d_in[4];
    const float* b_head = (const float*)d_in[5];
    float* out = (float*)d_out;

    float*    drive = (float*)d_ws;
    uint32_t* mask  = (uint32_t*)((char*)d_ws + 134217728u);
    unsigned long long* flags = (unsigned long long*)(mask + (TT * BB * 64));
    uint32_t* hist  = (uint32_t*)(flags + TT * BB);
    uint32_t* state = hist + 256;
    uint32_t* cnts  = state + 8;

    // zero flags + hist + state + cnts (contiguous; mask fully overwritten before read)
    k_init<<<64, 256, 0, stream>>>((uint32_t*)flags, TT * BB * 2 + 256 + 8 + 2);

    for (int p = 0; p < 4; ++p) {
        k_hist<<<1024, 256, 0, stream>>>(w_rec, hist, state, p);
        k_select<<<1, 256, 0, stream>>>(hist, state, p);
    }
    k_maskcount<<<1024, 256, 0, stream>>>(w_rec, state, cnts);

    k_drive<<<dim3(128, 16), 256, 0, stream>>>(x, w_in, b_in, drive);

    k_scan<<<512, 256, 0, stream>>>(w_rec, drive, mask, flags, cnts);

    k_head<<<TT * BB, 128, 0, stream>>>(mask, w_head, b_head, out + BB * DOUT);
    k_readout<<<BB, 128, 0, stream>>>(out + BB * DOUT, out);
    k_scalars<<<1, 64, 0, stream>>>(cnts, out);
}